// Round 10
// baseline (269.227 us; speedup 1.0000x reference)
//
#include <hip/hip_runtime.h>
#include <math.h>

#define HEADS 12
#define DH    64
#define Dm    768
#define I3    2304
#define Nn    1024
#define Mm    4096
#define BHt   48
#define LOG2E 1.4426950408889634f

// minmax pair indices
#define P_X  0
#define P_W1 1
#define P_Q  2
#define P_K  3
#define P_V  4
#define P_A  5
#define P_O  6
#define P_W2 7

typedef int v4i __attribute__((ext_vector_type(4)));

#if __has_builtin(__builtin_amdgcn_exp2f)
#define EXP2(x) __builtin_amdgcn_exp2f(x)
#else
#define EXP2(x) exp2f(x)
#endif

// ---------- helpers ----------
__device__ inline unsigned encf(float f) {
    unsigned u = __float_as_uint(f);
    return (u & 0x80000000u) ? ~u : (u | 0x80000000u);
}
__device__ inline float decf(unsigned u) {
    return (u & 0x80000000u) ? __uint_as_float(u & 0x7fffffffu) : __uint_as_float(~u);
}
__device__ inline void get_sz(const unsigned* scal, int pair, float* s, float* z) {
    float mn = decf(scal[2 * pair]);
    float mx = decf(scal[2 * pair + 1]);
    float ss = (mx - mn) / 15.0f;
    *s = ss;
    *z = rintf(15.0f - mx / ss);
}

// ---------- kernels ----------
// init scal + zero rowsum_xqkv (4096) and colsum_vq (3072)
__global__ __launch_bounds__(256) void k_init(unsigned* scal, float* z1, int n1, float* z2, int n2) {
    int g = blockIdx.x * 256 + threadIdx.x;
    if (g < n1) z1[g] = 0.f;
    if (g < n2) z2[g] = 0.f;
    if (g < 8) { scal[2 * g] = 0xFFFFFFFFu; scal[2 * g + 1] = 0u; }
}

// fused minmax of x (4096x768), w_qkv (2304x768), w_out (768x768); all cols=768
__global__ __launch_bounds__(256) void k_minmax3(const float* x, const float* w1, const float* w2,
                                                 unsigned* scal) {
    __shared__ float rmn[256], rmx[256];
    int bid = blockIdx.x, tid = threadIdx.x;
    const float* src; int rows, pair, b0, nb;
    if (bid < 256)      { src = x;  rows = 4096; pair = P_X;  b0 = 0;   nb = 256; }
    else if (bid < 384) { src = w1; rows = 2304; pair = P_W1; b0 = 256; nb = 128; }
    else                { src = w2; rows = 768;  pair = P_W2; b0 = 384; nb = 64;  }
    float mn = INFINITY, mx = -INFINITY;
    for (int r = bid - b0; r < rows; r += nb) {
        const float* row = src + (long)r * 768;
#pragma unroll
        for (int k = 0; k < 3; ++k) {
            float v = row[tid + k * 256];
            mn = fminf(mn, v); mx = fmaxf(mx, v);
        }
    }
    rmn[tid] = mn; rmx[tid] = mx; __syncthreads();
    for (int s = 128; s > 0; s >>= 1) {
        if (tid < s) { rmn[tid] = fminf(rmn[tid], rmn[tid + s]); rmx[tid] = fmaxf(rmx[tid], rmx[tid + s]); }
        __syncthreads();
    }
    if (tid == 0) {
        atomicMin(&scal[2 * pair], encf(rmn[0]));
        atomicMax(&scal[2 * pair + 1], encf(rmx[0]));
    }
}

// fused quantization of x / w_qkv / w_out (cols=768) -> int8 + row sums
__global__ __launch_bounds__(256) void k_quant3(const float* x, const float* w1, const float* w2,
                                                const unsigned* scal,
                                                signed char* xq, signed char* wq, signed char* w2q,
                                                float* rs_x, float* rs_w1, float* rs_w2) {
    __shared__ float red[256];
    int bid = blockIdx.x, tid = threadIdx.x;
    const float* src; signed char* dq; float* rs; int pair, r;
    if (bid < 4096)      { src = x;  dq = xq;  rs = rs_x;  pair = P_X;  r = bid; }
    else if (bid < 6400) { src = w1; dq = wq;  rs = rs_w1; pair = P_W1; r = bid - 4096; }
    else                 { src = w2; dq = w2q; rs = rs_w2; pair = P_W2; r = bid - 6400; }
    float s, z; get_sz(scal, pair, &s, &z);
    const float* row = src + (long)r * 768;
    signed char* drow = dq + (long)r * 768;
    float acc = 0.f;
#pragma unroll
    for (int k = 0; k < 3; ++k) {
        int c = tid + k * 256;
        float q = rintf(row[c] / s + z);
        drow[c] = (signed char)(int)q;
        acc += q;
    }
    red[tid] = acc; __syncthreads();
    for (int s2 = 128; s2 > 0; s2 >>= 1) { if (tid < s2) red[tid] += red[tid + s2]; __syncthreads(); }
    if (tid == 0) rs[r] = red[0];
}

// single-array quant (for out_mat -> oq), cols=768
__global__ __launch_bounds__(256) void k_quant_rows(const float* src, const unsigned* scal, int pair,
                                                    signed char* dq, float* rowsum) {
    __shared__ float red[256];
    int r = blockIdx.x, tid = threadIdx.x;
    float s, z; get_sz(scal, pair, &s, &z);
    const float* row = src + (long)r * 768;
    signed char* drow = dq + (long)r * 768;
    float acc = 0.f;
#pragma unroll
    for (int k = 0; k < 3; ++k) {
        int c = tid + k * 256;
        float q = rintf(row[c] / s + z);
        drow[c] = (signed char)(int)q;
        acc += q;
    }
    red[tid] = acc; __syncthreads();
    for (int s2 = 128; s2 > 0; s2 >>= 1) { if (tid < s2) red[tid] += red[tid + s2]; __syncthreads(); }
    if (tid == 0) rowsum[r] = red[0];
}

// MFMA int8 GEMM, block tile 128x128, BK=64 bytes, LDS-staged with register double-buffer.
__global__ __launch_bounds__(256) void k_gemm_mfma(const signed char* A, const signed char* B,
                                                   const float* colsumB, const float* rowsumA,
                                                   const float* bias, float* C, int K, int ldC,
                                                   const unsigned* scal, int pairA, int pairB,
                                                   float corrK, int do_stats, float* rowsum_out,
                                                   unsigned* scal_mm) {
    __shared__ __align__(16) signed char As[128 * 64];
    __shared__ __align__(16) signed char Bs[128 * 64];
    __shared__ float red[256];
    int tid = threadIdx.x;
    int wave = tid >> 6, lane = tid & 63;
    int col16 = lane & 15, quad = lane >> 4;
    long rowbase = (long)blockIdx.y * 128;
    long colbase = (long)blockIdx.x * 128;

    int c4 = tid & 3, r4 = tid >> 2;
    const signed char* ag0 = A + (rowbase + r4) * K + c4 * 16;
    const signed char* ag1 = A + (rowbase + r4 + 64) * K + c4 * 16;
    const signed char* bg0 = B + (colbase + r4) * K + c4 * 16;
    const signed char* bg1 = B + (colbase + r4 + 64) * K + c4 * 16;
    int soff0 = ((r4 >> 4) << 10) + (c4 << 8) + ((r4 & 15) << 4);
    int soff1 = soff0 + 4096;

    v4i ra0 = *(const v4i*)ag0;
    v4i ra1 = *(const v4i*)ag1;
    v4i rb0 = *(const v4i*)bg0;
    v4i rb1 = *(const v4i*)bg1;

    const int afrag_off = wave * 2048 + quad * 256 + col16 * 16;
    const int bfrag_off = quad * 256 + col16 * 16;
    v4i acc[2][8] = {};
    int nk = K >> 6;
    for (int kt = 0; kt < nk; ++kt) {
        *(v4i*)(As + soff0) = ra0;
        *(v4i*)(As + soff1) = ra1;
        *(v4i*)(Bs + soff0) = rb0;
        *(v4i*)(Bs + soff1) = rb1;
        __syncthreads();
        if (kt + 1 < nk) {
            int ko = (kt + 1) << 6;
            ra0 = *(const v4i*)(ag0 + ko);
            ra1 = *(const v4i*)(ag1 + ko);
            rb0 = *(const v4i*)(bg0 + ko);
            rb1 = *(const v4i*)(bg1 + ko);
        }
        v4i af0 = *(const v4i*)(As + afrag_off);
        v4i af1 = *(const v4i*)(As + afrag_off + 1024);
        v4i bf[8];
#pragma unroll
        for (int g = 0; g < 8; ++g) bf[g] = *(const v4i*)(Bs + bfrag_off + g * 1024);
#pragma unroll
        for (int g = 0; g < 8; ++g) {
            acc[0][g] = __builtin_amdgcn_mfma_i32_16x16x64_i8(af0, bf[g], acc[0][g], 0, 0, 0);
            acc[1][g] = __builtin_amdgcn_mfma_i32_16x16x64_i8(af1, bf[g], acc[1][g], 0, 0, 0);
        }
        __syncthreads();
    }

    float sA, zA, sB, zB;
    get_sz(scal, pairA, &sA, &zA);
    get_sz(scal, pairB, &sB, &zB);
    float sAB = sA * sB;
    float zz = (zA * zB) * corrK;
    float vmn = INFINITY, vmx = -INFINITY;
    float rowpart[2][4] = {};
#pragma unroll
    for (int i2 = 0; i2 < 2; ++i2)
#pragma unroll
        for (int g = 0; g < 8; ++g) {
            long col = colbase + g * 16 + col16;
            float cs = colsumB[col] * zA;
            float bv = bias ? bias[col] : 0.f;
#pragma unroll
            for (int r = 0; r < 4; ++r) {
                long row = rowbase + wave * 32 + i2 * 16 + quad * 4 + r;
                float v = ((float)acc[i2][g][r] - cs - rowsumA[row] * zB + zz) * sAB + bv;
                C[row * ldC + col] = v;
                rowpart[i2][r] += v;
                vmn = fminf(vmn, v); vmx = fmaxf(vmx, v);
            }
        }
    if (do_stats) {
#pragma unroll
        for (int i2 = 0; i2 < 2; ++i2)
#pragma unroll
            for (int r = 0; r < 4; ++r) {
                float s = rowpart[i2][r];
                s += __shfl_xor(s, 1); s += __shfl_xor(s, 2);
                s += __shfl_xor(s, 4); s += __shfl_xor(s, 8);
                if (col16 == 0)
                    atomicAdd(&rowsum_out[rowbase + wave * 32 + i2 * 16 + quad * 4 + r], s);
            }
        int pair = P_Q + (int)(colbase / 768);
        red[tid] = vmx; __syncthreads();
        for (int s = 128; s > 0; s >>= 1) { if (tid < s) red[tid] = fmaxf(red[tid], red[tid + s]); __syncthreads(); }
        if (tid == 0) atomicMax(&scal_mm[2 * pair + 1], encf(red[0]));
        __syncthreads();
        red[tid] = vmn; __syncthreads();
        for (int s = 128; s > 0; s >>= 1) { if (tid < s) red[tid] = fminf(red[tid], red[tid + s]); __syncthreads(); }
        if (tid == 0) atomicMin(&scal_mm[2 * pair], encf(red[0]));
    }
}

// quantize q/k/v, 64 i-rows per block. qq,kq row-contig; vqT via LDS transpose (16B stores).
// cskc[j] = colsum_kq[j]*zq*csc*LOG2E (log2-domain constant), colsum_vq via exact atomicAdd.
__global__ __launch_bounds__(256) void k_quant_qkv2(const float* xqkv, const unsigned* scal,
                                                    signed char* qq, signed char* kq, signed char* vqT,
                                                    float* rowsum_qq, float* cskc, float* colsum_vq) {
    __shared__ __align__(16) signed char vt[64 * 80];   // [d][i_local], stride 80
    __shared__ float vred[4][64];
    int blk = blockIdx.x;
    int bh = blk >> 4, itile = blk & 15;
    int tid = threadIdx.x;
    int wave = tid >> 6, d = tid & 63;
    int b = bh / HEADS, h = bh - HEADS * b;
    float sq, zq, sk, zk, sv, zv;
    get_sz(scal, P_Q, &sq, &zq);
    get_sz(scal, P_K, &sk, &zk);
    get_sz(scal, P_V, &sv, &zv);
    float zqcsc2 = zq * ((0.125f * sq) * sk) * LOG2E;
    int vb = 0;
    float vsum = 0.f;
    for (int ir = 0; ir < 16; ++ir) {
        int il = wave * 16 + ir;
        int i = itile * 64 + il;
        const float* row = xqkv + ((long)b * Nn + i) * I3 + h * DH;
        float q = rintf(row[d] / sq + zq);
        float k = rintf(row[768 + d] / sk + zk);
        float v = rintf(row[1536 + d] / sv + zv);
        long o = ((long)bh * Nn + i) * 64 + d;
        qq[o] = (signed char)(int)q;
        kq[o] = (signed char)(int)k;
        vsum += v;
        vb |= ((int)v & 0xff) << ((ir & 3) * 8);
        if ((ir & 3) == 3) {
            *(int*)(vt + d * 80 + (il & ~3)) = vb;
            vb = 0;
        }
        float s1 = q, s2 = k;
        for (int off = 32; off > 0; off >>= 1) {
            s1 += __shfl_down(s1, off);
            s2 += __shfl_down(s2, off);
        }
        if (d == 0) { rowsum_qq[bh * Nn + i] = s1; cskc[bh * Nn + i] = s2 * zqcsc2; }
    }
    vred[wave][d] = vsum;
    __syncthreads();
    int dd = tid >> 2, c = tid & 3;
    *(v4i*)(vqT + ((long)bh * 64 + dd) * 1024 + itile * 64 + c * 16) = *(const v4i*)(vt + dd * 80 + c * 16);
    if (tid < 64)   // exact: integer-valued floats, order-free
        atomicAdd(&colsum_vq[bh * 64 + tid],
                  ((vred[0][tid] + vred[1][tid]) + vred[2][tid]) + vred[3][tid]);
}

// Pass A v7: 512 threads, 8 waves. Wave w: rowgroup w&3 (16 rows), key-half w>>2 (512 keys).
// Online softmax (log2 domain), exact cross-lane merge, then exact pairwise half-merge via LDS.
__global__ __launch_bounds__(512) void k_attn_a7(const signed char* qq, const signed char* kq,
                                                 const float* rowsum_qq, const float* cskc,
                                                 unsigned* scal, float* rowmax, float* sumexp) {
    __shared__ float Wm[4][16], Wse[4][16], Wmin[4][16];
    __shared__ float red[512];
    int blk = blockIdx.x;
    int bh = blk >> 4, itile = blk & 15;
    int tid = threadIdx.x;
    int wave = tid >> 6, lane = tid & 63;
    int col16 = lane & 15, quad = lane >> 4;
    int wrg = wave & 3, kh = wave >> 2;
    int rowbase = itile * 64 + wrg * 16;
    const signed char* kbase = kq + (long)bh * Nn * 64;
    const float* ck = cskc + bh * Nn;
    v4i afrag = *(const v4i*)(qq + ((long)bh * Nn + rowbase + col16) * 64 + quad * 16);
    float sq, zq, sk, zk;
    get_sz(scal, P_Q, &sq, &zq);
    get_sz(scal, P_K, &sk, &zk);
    float csc2 = ((0.125f * sq) * sk) * LOG2E;
    float rzc[4];
#pragma unroll
    for (int r = 0; r < 4; ++r)
        rzc[r] = rowsum_qq[bh * Nn + rowbase + quad * 4 + r] * zk * csc2;
    v4i zero = {0, 0, 0, 0};
    float m[4]    = {-INFINITY, -INFINITY, -INFINITY, -INFINITY};
    float se[4]   = {0.f, 0.f, 0.f, 0.f};
    float lmin[4] = {INFINITY, INFINITY, INFINITY, INFINITY};
    for (int jt = 0; jt < 32; ++jt) {
        int grp = kh * 32 + jt;
        v4i bfrag = *(const v4i*)(kbase + (long)(grp * 16 + col16) * 64 + quad * 16);
        v4i d = __builtin_amdgcn_mfma_i32_16x16x64_i8(afrag, bfrag, zero, 0, 0, 0);
        float ckv = ck[grp * 16 + col16];
#pragma unroll
        for (int r = 0; r < 4; ++r) {
            float dv = fmaf((float)d[r], csc2, -(ckv + rzc[r]));
            lmin[r] = fminf(lmin[r], dv);
            float mn = fmaxf(m[r], dv);
            se[r] = fmaf(se[r], EXP2(m[r] - mn), EXP2(dv - mn));
            m[r] = mn;
        }
    }
#pragma unroll
    for (int r = 0; r < 4; ++r) {
#pragma unroll
        for (int off = 1; off < 16; off <<= 1) {
            float mo = __shfl_xor(m[r], off);
            float so = __shfl_xor(se[r], off);
            float mino = __shfl_xor(lmin[r], off);
            float mn = fmaxf(m[r], mo);
            se[r] = fmaf(se[r], EXP2(m[r] - mn), so * EXP2(mo - mn));
            m[r] = mn;
            lmin[r] = fminf(lmin[r], mino);
        }
    }
    if (kh == 1 && col16 == 0) {
#pragma unroll
        for (int r = 0; r < 4; ++r) {
            Wm[wrg][quad * 4 + r] = m[r];
            Wse[wrg][quad * 4 + r] = se[r];
            Wmin[wrg][quad * 4 + r] = lmin[r];
        }
    }
    __syncthreads();
    float amax_c = -INFINITY, amin_c = INFINITY;
    if (kh == 0 && col16 == 0) {
#pragma unroll
        for (int r = 0; r < 4; ++r) {
            int row = quad * 4 + r;
            float mo = Wm[wrg][row], so = Wse[wrg][row], mino = Wmin[wrg][row];
            float mn = fmaxf(m[r], mo);
            float sef = fmaf(se[r], EXP2(m[r] - mn), so * EXP2(mo - mn));
            float lmn = fminf(lmin[r], mino);
            int grow = bh * Nn + rowbase + row;
            rowmax[grow] = mn;          // log2 units
            sumexp[grow] = sef;
            amax_c = fmaxf(amax_c, 1.0f / sef);
            amin_c = fminf(amin_c, EXP2(lmn - mn) / sef);
        }
    }
    red[tid] = amax_c; __syncthreads();
    for (int s = 256; s > 0; s >>= 1) { if (tid < s) red[tid] = fmaxf(red[tid], red[tid + s]); __syncthreads(); }
    if (tid == 0) atomicMax(&scal[2 * P_A + 1], encf(red[0]));
    __syncthreads();
    red[tid] = amin_c; __syncthreads();
    for (int s = 256; s > 0; s >>= 1) { if (tid < s) red[tid] = fminf(red[tid], red[tid + s]); __syncthreads(); }
    if (tid == 0) atomicMin(&scal[2 * P_A], encf(red[0]));
}

// Pass B v7: 512 threads, 8 waves. Wave w: rowgroup w&3 (16 rows), key-half w>>2 (8 chunks of 64).
// LOG2-domain exp, ones-MFMA row sums, per-wave Aq LDS relayout (dbuf), integer cross-half
// accPV/accOnes merge via LDS. Fused P_O minmax.
__global__ __launch_bounds__(512) void k_attn_b7(const signed char* qq, const signed char* kq,
                                                 const signed char* vqT, const float* rowsum_qq,
                                                 const float* cskc, const float* colsum_vq,
                                                 const float* rowmax, const float* sumexp,
                                                 unsigned* scal, float* out_mat) {
    __shared__ __align__(16) signed char AqB[16384];   // loop: 8 waves x 1KB x dbuf; after: accPV exchange
    __shared__ __align__(16) v4i onesX[4][64];
    __shared__ float red[512];
    int blk = blockIdx.x;
    int bh = blk >> 4, itile = blk & 15;
    int tid = threadIdx.x;
    int wave = tid >> 6, lane = tid & 63;
    int col16 = lane & 15, quad = lane >> 4;
    int wrg = wave & 3, kh = wave >> 2;
    int rowbase = itile * 64 + wrg * 16;
    int b = bh / HEADS, h = bh - HEADS * b;
    const signed char* kbase = kq + (long)bh * Nn * 64;
    const signed char* vbase = vqT + (long)bh * 64 * 1024;
    const float* ck = cskc + bh * Nn;
    v4i afrag = *(const v4i*)(qq + ((long)bh * Nn + rowbase + col16) * 64 + quad * 16);
    float sq, zq, sk, zk, sv, zv, sa, za;
    get_sz(scal, P_Q, &sq, &zq);
    get_sz(scal, P_K, &sk, &zk);
    get_sz(scal, P_V, &sv, &zv);
    get_sz(scal, P_A, &sa, &za);
    float csc2 = ((0.125f * sq) * sk) * LOG2E;
    float roff[4], crcp[4];
#pragma unroll
    for (int r = 0; r < 4; ++r) {
        int row = bh * Nn + rowbase + quad * 4 + r;
        roff[r] = rowsum_qq[row] * zk * csc2 + rowmax[row];   // log2 units
        crcp[r] = 1.0f / (sumexp[row] * sa);
    }
    v4i accPV[4] = {};
    v4i accOnes = {0, 0, 0, 0};
    v4i zero = {0, 0, 0, 0};
    v4i ones = {0x01010101, 0x01010101, 0x01010101, 0x01010101};
    for (int ch = 0; ch < 8; ++ch) {
        signed char* myAq = AqB + (ch & 1) * 8192 + wave * 1024;
#pragma unroll
        for (int t = 0; t < 4; ++t) {
            int grp = kh * 32 + ch * 4 + t;
            v4i bfrag = *(const v4i*)(kbase + (long)(grp * 16 + col16) * 64 + quad * 16);
            v4i d = __builtin_amdgcn_mfma_i32_16x16x64_i8(afrag, bfrag, zero, 0, 0, 0);
            float ckv = ck[grp * 16 + col16];
#pragma unroll
            for (int r = 0; r < 4; ++r) {
                float es = fmaf((float)d[r], csc2, -(ckv + roff[r]));
                float fastv = fmaf(EXP2(es), crcp[r], za);
                float aqv = rintf(fastv);
                myAq[(quad * 4 + r) * 64 + t * 16 + col16] = (signed char)(int)aqv;
            }
        }
        asm volatile("s_waitcnt lgkmcnt(0)" ::: "memory");
        v4i pa = *(const v4i*)(myAq + col16 * 64 + quad * 16);
#pragma unroll
        for (int g = 0; g < 4; ++g) {
            v4i bv = *(const v4i*)(vbase + (long)(g * 16 + col16) * 1024 + kh * 512 + ch * 64 + quad * 16);
            accPV[g] = __builtin_amdgcn_mfma_i32_16x16x64_i8(pa, bv, accPV[g], 0, 0, 0);
        }
        accOnes = __builtin_amdgcn_mfma_i32_16x16x64_i8(pa, ones, accOnes, 0, 0, 0);
    }
    __syncthreads();   // all Aq use done; AqB reusable as exchange buffer
    if (kh == 1) {
        v4i* ex = (v4i*)AqB;
#pragma unroll
        for (int g = 0; g < 4; ++g) ex[((wrg * 64) + lane) * 4 + g] = accPV[g];
        onesX[wrg][lane] = accOnes;
    }
    __syncthreads();
    float vmn = INFINITY, vmx = -INFINITY;
    if (kh == 0) {
        const v4i* ex = (const v4i*)AqB;
        v4i po = onesX[wrg][lane];
        accOnes = accOnes + po;
        float sav = sa * sv;
        float zz = (za * zv) * 1024.0f;
#pragma unroll
        for (int g = 0; g < 4; ++g) {
            v4i pg = ex[((wrg * 64) + lane) * 4 + g];
            accPV[g] = accPV[g] + pg;
            int d = g * 16 + col16;
            float cs = colsum_vq[bh * 64 + d] * za;
#pragma unroll
            for (int r = 0; r < 4; ++r) {
                int i = rowbase + quad * 4 + r;
                float v = ((float)accPV[g][r] - cs - (float)accOnes[r] * zv + zz) * sav;
                out_mat[((long)b * Nn + i) * Dm + h * DH + d] = v;
                vmn = fminf(vmn, v); vmx = fmaxf(vmx, v);
            }
        }
    }
    red[tid] = vmx; __syncthreads();
    for (int s = 256; s > 0; s >>= 1) { if (tid < s) red[tid] = fmaxf(red[tid], red[tid + s]); __syncthreads(); }
    if (tid == 0) atomicMax(&scal[2 * P_O + 1], encf(red[0]));
    __syncthreads();
    red[tid] = vmn; __syncthreads();
    for (int s = 256; s > 0; s >>= 1) { if (tid < s) red[tid] = fminf(red[tid], red[tid + s]); __syncthreads(); }
    if (tid == 0) atomicMin(&scal[2 * P_O], encf(red[0]));
}

// ---------- launch ----------
extern "C" void kernel_launch(void* const* d_in, const int* in_sizes, int n_in,
                              void* d_out, int out_size, void* d_ws, size_t ws_size,
                              hipStream_t stream) {
    const float* x     = (const float*)d_in[0];
    const float* w_qkv = (const float*)d_in[1];
    const float* w_out = (const float*)d_in[2];
    const float* b_out = (const float*)d_in[3];

    char* ws = (char*)d_ws;
    size_t off = 0;
    auto alloc = [&](size_t n) -> char* {
        char* p = ws + off;
        off = (off + n + 255) & ~(size_t)255;
        return p;
    };
    unsigned*    scal        = (unsigned*)alloc(64);
    float*       xqkv        = (float*)alloc((size_t)Mm * I3 * 4);
    float*       out_mat     = (float*)alloc((size_t)Mm * Dm * 4);
    signed char* xq          = (signed char*)alloc((size_t)Mm * Dm);
    signed char* wq          = (signed char*)alloc((size_t)I3 * Dm);
    signed char* w2q         = (signed char*)alloc((size_t)Dm * Dm);
    signed char* oq          = (signed char*)alloc((size_t)Mm * Dm);
    signed char* qq          = (signed char*)alloc((size_t)BHt * Nn * DH);
    signed char* kq          = (signed char*)alloc((size_t)BHt * Nn * DH);
    signed char* vqT         = (signed char*)alloc((size_t)BHt * Nn * DH);
    float*       rowsum_xq   = (float*)alloc((size_t)Mm * 4);
    float*       colsum_w1   = (float*)alloc((size_t)I3 * 4);
    float*       colsum_w2   = (float*)alloc((size_t)Dm * 4);
    float*       rowsum_xqkv = (float*)alloc((size_t)Mm * 4);
    float*       rowsum_qq   = (float*)alloc((size_t)BHt * Nn * 4);
    float*       cskc        = (float*)alloc((size_t)BHt * Nn * 4);
    float*       colsum_vq   = (float*)alloc((size_t)BHt * DH * 4);
    float*       rowmax      = (float*)alloc((size_t)BHt * Nn * 4);
    float*       sumexp      = (float*)alloc((size_t)BHt * Nn * 4);
    float*       oq_rowsum   = (float*)alloc((size_t)Mm * 4);

    k_init<<<28, 256, 0, stream>>>(scal, rowsum_xqkv, Mm, colsum_vq, BHt * DH);

    k_minmax3<<<448, 256, 0, stream>>>(x, w_qkv, w_out, scal);
    k_quant3<<<7168, 256, 0, stream>>>(x, w_qkv, w_out, scal, xq, wq, w2q,
                                       rowsum_xq, colsum_w1, colsum_w2);

    {   // GEMM1 + fused xqkv row sums and Q/K/V minmax
        dim3 g(I3 / 128, Mm / 128);
        k_gemm_mfma<<<g, 256, 0, stream>>>(xq, wq, colsum_w1, rowsum_xq, nullptr, xqkv,
                                           Dm, I3, scal, P_X, P_W1, 768.0f,
                                           1, rowsum_xqkv, scal);
    }

    k_quant_qkv2<<<BHt * 16, 256, 0, stream>>>(xqkv, scal, qq, kq, vqT,
                                               rowsum_qq, cskc, colsum_vq);

    k_attn_a7<<<BHt * 16, 512, 0, stream>>>(qq, kq, rowsum_qq, cskc, scal, rowmax, sumexp);
    k_attn_b7<<<BHt * 16, 512, 0, stream>>>(qq, kq, vqT, rowsum_qq, cskc, colsum_vq,
                                            rowmax, sumexp, scal, out_mat);

    k_quant_rows<<<Mm, 256, 0, stream>>>(out_mat, scal, P_O, oq, oq_rowsum);

    {   // GEMM2 (+bias)
        dim3 g(Dm / 128, Mm / 128);
        k_gemm_mfma<<<g, 256, 0, stream>>>(oq, w2q, colsum_w2, rowsum_xqkv, b_out, (float*)d_out,
                                           Dm, Dm, scal, P_O, P_W2, 2304.0f,
                                           0, nullptr, nullptr);
    }
}

// Round 11
// 259.361 us; speedup vs baseline: 1.0380x; 1.0380x over previous
//
#include <hip/hip_runtime.h>
#include <math.h>

#define HEADS 12
#define DH    64
#define Dm    768
#define I3    2304
#define Nn    1024
#define Mm    4096
#define BHt   48
#define LOG2E 1.4426950408889634f

// minmax pair indices
#define P_X  0
#define P_W1 1
#define P_Q  2
#define P_K  3
#define P_V  4
#define P_A  5
#define P_O  6
#define P_W2 7

typedef int v4i __attribute__((ext_vector_type(4)));

#if __has_builtin(__builtin_amdgcn_exp2f)
#define EXP2(x) __builtin_amdgcn_exp2f(x)
#else
#define EXP2(x) exp2f(x)
#endif

// ---------- helpers ----------
__device__ inline unsigned encf(float f) {
    unsigned u = __float_as_uint(f);
    return (u & 0x80000000u) ? ~u : (u | 0x80000000u);
}
__device__ inline float decf(unsigned u) {
    return (u & 0x80000000u) ? __uint_as_float(u & 0x7fffffffu) : __uint_as_float(~u);
}
__device__ inline void get_sz(const unsigned* scal, int pair, float* s, float* z) {
    float mn = decf(scal[2 * pair]);
    float mx = decf(scal[2 * pair + 1]);
    float ss = (mx - mn) / 15.0f;
    *s = ss;
    *z = rintf(15.0f - mx / ss);
}

// ---------- kernels ----------
// init scal + zero rowsum_xqkv (4096) and colsum_vq (3072)
__global__ __launch_bounds__(256) void k_init(unsigned* scal, float* z1, int n1, float* z2, int n2) {
    int g = blockIdx.x * 256 + threadIdx.x;
    if (g < n1) z1[g] = 0.f;
    if (g < n2) z2[g] = 0.f;
    if (g < 8) { scal[2 * g] = 0xFFFFFFFFu; scal[2 * g + 1] = 0u; }
}

// fused minmax of x (4096x768), w_qkv (2304x768), w_out (768x768); all cols=768
__global__ __launch_bounds__(256) void k_minmax3(const float* x, const float* w1, const float* w2,
                                                 unsigned* scal) {
    __shared__ float rmn[256], rmx[256];
    int bid = blockIdx.x, tid = threadIdx.x;
    const float* src; int rows, pair, b0, nb;
    if (bid < 256)      { src = x;  rows = 4096; pair = P_X;  b0 = 0;   nb = 256; }
    else if (bid < 384) { src = w1; rows = 2304; pair = P_W1; b0 = 256; nb = 128; }
    else                { src = w2; rows = 768;  pair = P_W2; b0 = 384; nb = 64;  }
    float mn = INFINITY, mx = -INFINITY;
    for (int r = bid - b0; r < rows; r += nb) {
        const float* row = src + (long)r * 768;
#pragma unroll
        for (int k = 0; k < 3; ++k) {
            float v = row[tid + k * 256];
            mn = fminf(mn, v); mx = fmaxf(mx, v);
        }
    }
    rmn[tid] = mn; rmx[tid] = mx; __syncthreads();
    for (int s = 128; s > 0; s >>= 1) {
        if (tid < s) { rmn[tid] = fminf(rmn[tid], rmn[tid + s]); rmx[tid] = fmaxf(rmx[tid], rmx[tid + s]); }
        __syncthreads();
    }
    if (tid == 0) {
        atomicMin(&scal[2 * pair], encf(rmn[0]));
        atomicMax(&scal[2 * pair + 1], encf(rmx[0]));
    }
}

// fused quantization of x / w_qkv / w_out (cols=768) -> int8 + row sums
__global__ __launch_bounds__(256) void k_quant3(const float* x, const float* w1, const float* w2,
                                                const unsigned* scal,
                                                signed char* xq, signed char* wq, signed char* w2q,
                                                float* rs_x, float* rs_w1, float* rs_w2) {
    __shared__ float red[256];
    int bid = blockIdx.x, tid = threadIdx.x;
    const float* src; signed char* dq; float* rs; int pair, r;
    if (bid < 4096)      { src = x;  dq = xq;  rs = rs_x;  pair = P_X;  r = bid; }
    else if (bid < 6400) { src = w1; dq = wq;  rs = rs_w1; pair = P_W1; r = bid - 4096; }
    else                 { src = w2; dq = w2q; rs = rs_w2; pair = P_W2; r = bid - 6400; }
    float s, z; get_sz(scal, pair, &s, &z);
    const float* row = src + (long)r * 768;
    signed char* drow = dq + (long)r * 768;
    float acc = 0.f;
#pragma unroll
    for (int k = 0; k < 3; ++k) {
        int c = tid + k * 256;
        float q = rintf(row[c] / s + z);
        drow[c] = (signed char)(int)q;
        acc += q;
    }
    red[tid] = acc; __syncthreads();
    for (int s2 = 128; s2 > 0; s2 >>= 1) { if (tid < s2) red[tid] += red[tid + s2]; __syncthreads(); }
    if (tid == 0) rs[r] = red[0];
}

// single-array quant (for out_mat -> oq), cols=768. NOTE: no row sums — GEMM2's row
// correction uses rowsum_xqkv (faithful reference bug), oq row sums are never needed.
__global__ __launch_bounds__(256) void k_quant_rows(const float* src, const unsigned* scal, int pair,
                                                    signed char* dq) {
    int r = blockIdx.x, tid = threadIdx.x;
    float s, z; get_sz(scal, pair, &s, &z);
    const float* row = src + (long)r * 768;
    signed char* drow = dq + (long)r * 768;
#pragma unroll
    for (int k = 0; k < 3; ++k) {
        int c = tid + k * 256;
        float q = rintf(row[c] / s + z);
        drow[c] = (signed char)(int)q;
    }
}

// MFMA int8 GEMM, block tile 128x128, BK=64 bytes, LDS-staged with register double-buffer.
__global__ __launch_bounds__(256) void k_gemm_mfma(const signed char* A, const signed char* B,
                                                   const float* colsumB, const float* rowsumA,
                                                   const float* bias, float* C, int K, int ldC,
                                                   const unsigned* scal, int pairA, int pairB,
                                                   float corrK, int do_stats, float* rowsum_out,
                                                   unsigned* scal_mm) {
    __shared__ __align__(16) signed char As[128 * 64];
    __shared__ __align__(16) signed char Bs[128 * 64];
    __shared__ float red[256];
    int tid = threadIdx.x;
    int wave = tid >> 6, lane = tid & 63;
    int col16 = lane & 15, quad = lane >> 4;
    long rowbase = (long)blockIdx.y * 128;
    long colbase = (long)blockIdx.x * 128;

    int c4 = tid & 3, r4 = tid >> 2;
    const signed char* ag0 = A + (rowbase + r4) * K + c4 * 16;
    const signed char* ag1 = A + (rowbase + r4 + 64) * K + c4 * 16;
    const signed char* bg0 = B + (colbase + r4) * K + c4 * 16;
    const signed char* bg1 = B + (colbase + r4 + 64) * K + c4 * 16;
    int soff0 = ((r4 >> 4) << 10) + (c4 << 8) + ((r4 & 15) << 4);
    int soff1 = soff0 + 4096;

    v4i ra0 = *(const v4i*)ag0;
    v4i ra1 = *(const v4i*)ag1;
    v4i rb0 = *(const v4i*)bg0;
    v4i rb1 = *(const v4i*)bg1;

    const int afrag_off = wave * 2048 + quad * 256 + col16 * 16;
    const int bfrag_off = quad * 256 + col16 * 16;
    v4i acc[2][8] = {};
    int nk = K >> 6;
    for (int kt = 0; kt < nk; ++kt) {
        *(v4i*)(As + soff0) = ra0;
        *(v4i*)(As + soff1) = ra1;
        *(v4i*)(Bs + soff0) = rb0;
        *(v4i*)(Bs + soff1) = rb1;
        __syncthreads();
        if (kt + 1 < nk) {
            int ko = (kt + 1) << 6;
            ra0 = *(const v4i*)(ag0 + ko);
            ra1 = *(const v4i*)(ag1 + ko);
            rb0 = *(const v4i*)(bg0 + ko);
            rb1 = *(const v4i*)(bg1 + ko);
        }
        v4i af0 = *(const v4i*)(As + afrag_off);
        v4i af1 = *(const v4i*)(As + afrag_off + 1024);
        v4i bf[8];
#pragma unroll
        for (int g = 0; g < 8; ++g) bf[g] = *(const v4i*)(Bs + bfrag_off + g * 1024);
#pragma unroll
        for (int g = 0; g < 8; ++g) {
            acc[0][g] = __builtin_amdgcn_mfma_i32_16x16x64_i8(af0, bf[g], acc[0][g], 0, 0, 0);
            acc[1][g] = __builtin_amdgcn_mfma_i32_16x16x64_i8(af1, bf[g], acc[1][g], 0, 0, 0);
        }
        __syncthreads();
    }

    float sA, zA, sB, zB;
    get_sz(scal, pairA, &sA, &zA);
    get_sz(scal, pairB, &sB, &zB);
    float sAB = sA * sB;
    float zz = (zA * zB) * corrK;
    float vmn = INFINITY, vmx = -INFINITY;
    float rowpart[2][4] = {};
#pragma unroll
    for (int i2 = 0; i2 < 2; ++i2)
#pragma unroll
        for (int g = 0; g < 8; ++g) {
            long col = colbase + g * 16 + col16;
            float cs = colsumB[col] * zA;
            float bv = bias ? bias[col] : 0.f;
#pragma unroll
            for (int r = 0; r < 4; ++r) {
                long row = rowbase + wave * 32 + i2 * 16 + quad * 4 + r;
                float v = ((float)acc[i2][g][r] - cs - rowsumA[row] * zB + zz) * sAB + bv;
                C[row * ldC + col] = v;
                rowpart[i2][r] += v;
                vmn = fminf(vmn, v); vmx = fmaxf(vmx, v);
            }
        }
    if (do_stats) {
#pragma unroll
        for (int i2 = 0; i2 < 2; ++i2)
#pragma unroll
            for (int r = 0; r < 4; ++r) {
                float s = rowpart[i2][r];
                s += __shfl_xor(s, 1); s += __shfl_xor(s, 2);
                s += __shfl_xor(s, 4); s += __shfl_xor(s, 8);
                if (col16 == 0)
                    atomicAdd(&rowsum_out[rowbase + wave * 32 + i2 * 16 + quad * 4 + r], s);
            }
        int pair = P_Q + (int)(colbase / 768);
        red[tid] = vmx; __syncthreads();
        for (int s = 128; s > 0; s >>= 1) { if (tid < s) red[tid] = fmaxf(red[tid], red[tid + s]); __syncthreads(); }
        if (tid == 0) atomicMax(&scal_mm[2 * pair + 1], encf(red[0]));
        __syncthreads();
        red[tid] = vmn; __syncthreads();
        for (int s = 128; s > 0; s >>= 1) { if (tid < s) red[tid] = fminf(red[tid], red[tid + s]); __syncthreads(); }
        if (tid == 0) atomicMin(&scal_mm[2 * pair], encf(red[0]));
    }
}

// quantize q/k/v, 64 i-rows per block. qq,kq row-contig; vqT via LDS transpose (16B stores).
// cskc[j] = colsum_kq[j]*zq*csc*LOG2E (log2-domain constant), colsum_vq via exact atomicAdd.
__global__ __launch_bounds__(256) void k_quant_qkv2(const float* xqkv, const unsigned* scal,
                                                    signed char* qq, signed char* kq, signed char* vqT,
                                                    float* rowsum_qq, float* cskc, float* colsum_vq) {
    __shared__ __align__(16) signed char vt[64 * 80];   // [d][i_local], stride 80
    __shared__ float vred[4][64];
    int blk = blockIdx.x;
    int bh = blk >> 4, itile = blk & 15;
    int tid = threadIdx.x;
    int wave = tid >> 6, d = tid & 63;
    int b = bh / HEADS, h = bh - HEADS * b;
    float sq, zq, sk, zk, sv, zv;
    get_sz(scal, P_Q, &sq, &zq);
    get_sz(scal, P_K, &sk, &zk);
    get_sz(scal, P_V, &sv, &zv);
    float zqcsc2 = zq * ((0.125f * sq) * sk) * LOG2E;
    int vb = 0;
    float vsum = 0.f;
    for (int ir = 0; ir < 16; ++ir) {
        int il = wave * 16 + ir;
        int i = itile * 64 + il;
        const float* row = xqkv + ((long)b * Nn + i) * I3 + h * DH;
        float q = rintf(row[d] / sq + zq);
        float k = rintf(row[768 + d] / sk + zk);
        float v = rintf(row[1536 + d] / sv + zv);
        long o = ((long)bh * Nn + i) * 64 + d;
        qq[o] = (signed char)(int)q;
        kq[o] = (signed char)(int)k;
        vsum += v;
        vb |= ((int)v & 0xff) << ((ir & 3) * 8);
        if ((ir & 3) == 3) {
            *(int*)(vt + d * 80 + (il & ~3)) = vb;
            vb = 0;
        }
        float s1 = q, s2 = k;
        for (int off = 32; off > 0; off >>= 1) {
            s1 += __shfl_down(s1, off);
            s2 += __shfl_down(s2, off);
        }
        if (d == 0) { rowsum_qq[bh * Nn + i] = s1; cskc[bh * Nn + i] = s2 * zqcsc2; }
    }
    vred[wave][d] = vsum;
    __syncthreads();
    int dd = tid >> 2, c = tid & 3;
    *(v4i*)(vqT + ((long)bh * 64 + dd) * 1024 + itile * 64 + c * 16) = *(const v4i*)(vt + dd * 80 + c * 16);
    if (tid < 64)   // exact: integer-valued floats, order-free
        atomicAdd(&colsum_vq[bh * 64 + tid],
                  ((vred[0][tid] + vred[1][tid]) + vred[2][tid]) + vred[3][tid]);
}

// Pass A v8 (= r9's a6, measured best): 64 q-rows/block, online softmax in LOG2 domain,
// K register prefetch. rowmax stored in log2 units.
__global__ __launch_bounds__(256) void k_attn_a8(const signed char* qq, const signed char* kq,
                                                 const float* rowsum_qq, const float* cskc,
                                                 unsigned* scal, float* rowmax, float* sumexp) {
    __shared__ float red[256];
    int blk = blockIdx.x;
    int bh = blk >> 4, itile = blk & 15;
    int tid = threadIdx.x;
    int wave = tid >> 6, lane = tid & 63;
    int col16 = lane & 15, quad = lane >> 4;
    int rowbase = itile * 64 + wave * 16;
    const signed char* kbase = kq + (long)bh * Nn * 64;
    const float* ck = cskc + bh * Nn;
    v4i afrag = *(const v4i*)(qq + ((long)bh * Nn + rowbase + col16) * 64 + quad * 16);
    float sq, zq, sk, zk;
    get_sz(scal, P_Q, &sq, &zq);
    get_sz(scal, P_K, &sk, &zk);
    float csc2 = ((0.125f * sq) * sk) * LOG2E;
    float rzc[4];
#pragma unroll
    for (int r = 0; r < 4; ++r)
        rzc[r] = rowsum_qq[bh * Nn + rowbase + quad * 4 + r] * zk * csc2;
    v4i zero = {0, 0, 0, 0};
    float m[4]    = {-INFINITY, -INFINITY, -INFINITY, -INFINITY};
    float se[4]   = {0.f, 0.f, 0.f, 0.f};
    float lmin[4] = {INFINITY, INFINITY, INFINITY, INFINITY};
    const signed char* kf = kbase + (long)col16 * 64 + quad * 16;
    v4i kb[2][4];
#pragma unroll
    for (int t = 0; t < 4; ++t) kb[0][t] = *(const v4i*)(kf + (long)(t * 16) * 64);
#pragma unroll 2
    for (int ch = 0; ch < 16; ++ch) {
        int cur = ch & 1, nxt = cur ^ 1;
        int pch = (ch < 15) ? ch + 1 : 15;
#pragma unroll
        for (int t = 0; t < 4; ++t)
            kb[nxt][t] = *(const v4i*)(kf + (long)(pch * 64 + t * 16) * 64);
#pragma unroll
        for (int t = 0; t < 4; ++t) {
            v4i d = __builtin_amdgcn_mfma_i32_16x16x64_i8(afrag, kb[cur][t], zero, 0, 0, 0);
            float ckv = ck[ch * 64 + t * 16 + col16];
#pragma unroll
            for (int r = 0; r < 4; ++r) {
                float dv = fmaf((float)d[r], csc2, -(ckv + rzc[r]));
                lmin[r] = fminf(lmin[r], dv);
                float mn = fmaxf(m[r], dv);
                se[r] = fmaf(se[r], EXP2(m[r] - mn), EXP2(dv - mn));
                m[r] = mn;
            }
        }
    }
#pragma unroll
    for (int r = 0; r < 4; ++r) {
#pragma unroll
        for (int off = 1; off < 16; off <<= 1) {
            float mo = __shfl_xor(m[r], off);
            float so = __shfl_xor(se[r], off);
            float mino = __shfl_xor(lmin[r], off);
            float mn = fmaxf(m[r], mo);
            se[r] = fmaf(se[r], EXP2(m[r] - mn), so * EXP2(mo - mn));
            m[r] = mn;
            lmin[r] = fminf(lmin[r], mino);
        }
    }
    float amax_c = -INFINITY, amin_c = INFINITY;
    if (col16 == 0) {
#pragma unroll
        for (int r = 0; r < 4; ++r) {
            int grow = bh * Nn + rowbase + quad * 4 + r;
            rowmax[grow] = m[r];          // log2 units
            sumexp[grow] = se[r];
            amax_c = fmaxf(amax_c, 1.0f / se[r]);
            amin_c = fminf(amin_c, EXP2(lmin[r] - m[r]) / se[r]);
        }
    }
    red[tid] = amax_c; __syncthreads();
    for (int s = 128; s > 0; s >>= 1) { if (tid < s) red[tid] = fmaxf(red[tid], red[tid + s]); __syncthreads(); }
    if (tid == 0) atomicMax(&scal[2 * P_A + 1], encf(red[0]));
    __syncthreads();
    red[tid] = amin_c; __syncthreads();
    for (int s = 128; s > 0; s >>= 1) { if (tid < s) red[tid] = fminf(red[tid], red[tid + s]); __syncthreads(); }
    if (tid == 0) atomicMin(&scal[2 * P_A], encf(red[0]));
}

// Pass B v8: b4 structure + LOG2 exp + software-pipelined LDS roundtrip:
// read pa[ch] (written last iter) at top, V loads for ch, then quant ch+1 into other
// buffer, then PV MFMA — no asm barriers, compiler emits precise lgkmcnt(N).
__global__ __launch_bounds__(256) void k_attn_b8(const signed char* qq, const signed char* kq,
                                                 const signed char* vqT, const float* rowsum_qq,
                                                 const float* cskc, const float* colsum_vq,
                                                 const float* rowmax, const float* sumexp,
                                                 unsigned* scal, float* out_mat) {
    __shared__ __align__(16) signed char AqB[8192];
    __shared__ float red[256];
    int blk = blockIdx.x;
    int bh = blk >> 4, itile = blk & 15;
    int tid = threadIdx.x;
    int wave = tid >> 6, lane = tid & 63;
    int col16 = lane & 15, quad = lane >> 4;
    int rowbase = itile * 64 + wave * 16;
    int b = bh / HEADS, h = bh - HEADS * b;
    const signed char* kbase = kq + (long)bh * Nn * 64;
    const signed char* vbase = vqT + (long)bh * 64 * 1024;
    const float* ck = cskc + bh * Nn;
    v4i afrag = *(const v4i*)(qq + ((long)bh * Nn + rowbase + col16) * 64 + quad * 16);
    float sq, zq, sk, zk, sv, zv, sa, za;
    get_sz(scal, P_Q, &sq, &zq);
    get_sz(scal, P_K, &sk, &zk);
    get_sz(scal, P_V, &sv, &zv);
    get_sz(scal, P_A, &sa, &za);
    float csc2 = ((0.125f * sq) * sk) * LOG2E;
    float roff[4], crcp[4];
#pragma unroll
    for (int r = 0; r < 4; ++r) {
        int row = bh * Nn + rowbase + quad * 4 + r;
        roff[r] = rowsum_qq[row] * zk * csc2 + rowmax[row];   // log2 units
        crcp[r] = 1.0f / (sumexp[row] * sa);
    }
    v4i accPV[4] = {};
    float rs_a[4] = {0.f, 0.f, 0.f, 0.f};
    v4i zero = {0, 0, 0, 0};

#define QUANT_CHUNK(CH, BUF)                                                            \
    {                                                                                   \
        signed char* myAq = AqB + (BUF) * 4096 + wave * 1024;                           \
        _Pragma("unroll")                                                               \
        for (int t = 0; t < 4; ++t) {                                                   \
            int jt = (CH) * 4 + t;                                                      \
            v4i bfrag = *(const v4i*)(kbase + (long)(jt * 16 + col16) * 64 + quad * 16);\
            v4i d = __builtin_amdgcn_mfma_i32_16x16x64_i8(afrag, bfrag, zero, 0, 0, 0); \
            float ckv = ck[jt * 16 + col16];                                            \
            _Pragma("unroll")                                                           \
            for (int r = 0; r < 4; ++r) {                                               \
                float es = fmaf((float)d[r], csc2, -(ckv + roff[r]));                   \
                float fastv = fmaf(EXP2(es), crcp[r], za);                              \
                float aqv = rintf(fastv);                                               \
                rs_a[r] += aqv;                                                         \
                myAq[(quad * 4 + r) * 64 + t * 16 + col16] = (signed char)(int)aqv;     \
            }                                                                           \
        }                                                                               \
    }

    QUANT_CHUNK(0, 0)
    for (int ch = 0; ch < 16; ++ch) {
        int cur = ch & 1;
        // read pa for ch (writes issued last iteration -> latency already covered)
        v4i pa = *(const v4i*)(AqB + cur * 4096 + wave * 1024 + col16 * 64 + quad * 16);
        // V loads for ch (latency covered by next chunk's quant work below)
        v4i bv[4];
#pragma unroll
        for (int g = 0; g < 4; ++g)
            bv[g] = *(const v4i*)(vbase + (long)(g * 16 + col16) * 1024 + ch * 64 + quad * 16);
        if (ch < 15) QUANT_CHUNK(ch + 1, cur ^ 1)
#pragma unroll
        for (int g = 0; g < 4; ++g)
            accPV[g] = __builtin_amdgcn_mfma_i32_16x16x64_i8(pa, bv[g], accPV[g], 0, 0, 0);
    }
#undef QUANT_CHUNK

#pragma unroll
    for (int r = 0; r < 4; ++r)
        for (int off = 1; off < 16; off <<= 1) rs_a[r] += __shfl_xor(rs_a[r], off);
    float sav = sa * sv;
    float zz = (za * zv) * 1024.0f;
    float vmn = INFINITY, vmx = -INFINITY;
#pragma unroll
    for (int g = 0; g < 4; ++g) {
        int d = g * 16 + col16;
        float cs = colsum_vq[bh * 64 + d] * za;
#pragma unroll
        for (int r = 0; r < 4; ++r) {
            int i = rowbase + quad * 4 + r;
            float v = ((float)accPV[g][r] - cs - rs_a[r] * zv + zz) * sav;
            out_mat[((long)b * Nn + i) * Dm + h * DH + d] = v;
            vmn = fminf(vmn, v); vmx = fmaxf(vmx, v);
        }
    }
    red[tid] = vmx; __syncthreads();
    for (int s = 128; s > 0; s >>= 1) { if (tid < s) red[tid] = fmaxf(red[tid], red[tid + s]); __syncthreads(); }
    if (tid == 0) atomicMax(&scal[2 * P_O + 1], encf(red[0]));
    __syncthreads();
    red[tid] = vmn; __syncthreads();
    for (int s = 128; s > 0; s >>= 1) { if (tid < s) red[tid] = fminf(red[tid], red[tid + s]); __syncthreads(); }
    if (tid == 0) atomicMin(&scal[2 * P_O], encf(red[0]));
}

// ---------- launch ----------
extern "C" void kernel_launch(void* const* d_in, const int* in_sizes, int n_in,
                              void* d_out, int out_size, void* d_ws, size_t ws_size,
                              hipStream_t stream) {
    const float* x     = (const float*)d_in[0];
    const float* w_qkv = (const float*)d_in[1];
    const float* w_out = (const float*)d_in[2];
    const float* b_out = (const float*)d_in[3];

    char* ws = (char*)d_ws;
    size_t off = 0;
    auto alloc = [&](size_t n) -> char* {
        char* p = ws + off;
        off = (off + n + 255) & ~(size_t)255;
        return p;
    };
    unsigned*    scal        = (unsigned*)alloc(64);
    float*       xqkv        = (float*)alloc((size_t)Mm * I3 * 4);
    float*       out_mat     = (float*)alloc((size_t)Mm * Dm * 4);
    signed char* xq          = (signed char*)alloc((size_t)Mm * Dm);
    signed char* wq          = (signed char*)alloc((size_t)I3 * Dm);
    signed char* w2q         = (signed char*)alloc((size_t)Dm * Dm);
    signed char* oq          = (signed char*)alloc((size_t)Mm * Dm);
    signed char* qq          = (signed char*)alloc((size_t)BHt * Nn * DH);
    signed char* kq          = (signed char*)alloc((size_t)BHt * Nn * DH);
    signed char* vqT         = (signed char*)alloc((size_t)BHt * Nn * DH);
    float*       rowsum_xq   = (float*)alloc((size_t)Mm * 4);
    float*       colsum_w1   = (float*)alloc((size_t)I3 * 4);
    float*       colsum_w2   = (float*)alloc((size_t)Dm * 4);
    float*       rowsum_xqkv = (float*)alloc((size_t)Mm * 4);
    float*       rowsum_qq   = (float*)alloc((size_t)BHt * Nn * 4);
    float*       cskc        = (float*)alloc((size_t)BHt * Nn * 4);
    float*       colsum_vq   = (float*)alloc((size_t)BHt * DH * 4);
    float*       rowmax      = (float*)alloc((size_t)BHt * Nn * 4);
    float*       sumexp      = (float*)alloc((size_t)BHt * Nn * 4);

    k_init<<<28, 256, 0, stream>>>(scal, rowsum_xqkv, Mm, colsum_vq, BHt * DH);

    k_minmax3<<<448, 256, 0, stream>>>(x, w_qkv, w_out, scal);
    k_quant3<<<7168, 256, 0, stream>>>(x, w_qkv, w_out, scal, xq, wq, w2q,
                                       rowsum_xq, colsum_w1, colsum_w2);

    {   // GEMM1 + fused xqkv row sums and Q/K/V minmax
        dim3 g(I3 / 128, Mm / 128);
        k_gemm_mfma<<<g, 256, 0, stream>>>(xq, wq, colsum_w1, rowsum_xq, nullptr, xqkv,
                                           Dm, I3, scal, P_X, P_W1, 768.0f,
                                           1, rowsum_xqkv, scal);
    }

    k_quant_qkv2<<<BHt * 16, 256, 0, stream>>>(xqkv, scal, qq, kq, vqT,
                                               rowsum_qq, cskc, colsum_vq);

    k_attn_a8<<<BHt * 16, 256, 0, stream>>>(qq, kq, rowsum_qq, cskc, scal, rowmax, sumexp);
    k_attn_b8<<<BHt * 16, 256, 0, stream>>>(qq, kq, vqT, rowsum_qq, cskc, colsum_vq,
                                            rowmax, sumexp, scal, out_mat);

    k_quant_rows<<<Mm, 256, 0, stream>>>(out_mat, scal, P_O, oq);

    {   // GEMM2 (+bias)
        dim3 g(Dm / 128, Mm / 128);
        k_gemm_mfma<<<g, 256, 0, stream>>>(oq, w2q, colsum_w2, rowsum_xqkv, b_out, (float*)d_out,
                                           Dm, Dm, scal, P_O, P_W2, 2304.0f,
                                           0, nullptr, nullptr);
    }
}